// Round 1
// baseline (2194.757 us; speedup 1.0000x reference)
//
#include <hip/hip_runtime.h>

// QuantizedLinear: out[M=8192, N=16384] = (x[M,K=4096] @ (w_int[N,K]*scale[N]).T) + bias[N]
// Strategy: convert x (fp32->bf16, RTNE) and w (int32->bf16, EXACT for |w|<=127) into
// workspace, then bf16 MFMA GEMM (m97 structure: 128x128 tile, BK=64,
// global_load_lds width=16, 16x16x32 MFMA). Scale+bias fused in fp32 epilogue.

typedef __bf16 bf16x8 __attribute__((ext_vector_type(8)));
typedef float floatx4 __attribute__((ext_vector_type(4)));
typedef unsigned short ushort_t;

#define GEMM_M 8192
#define GEMM_N 16384
#define GEMM_K 4096

__device__ inline unsigned int f2bf(float f) {
    // round-to-nearest-even fp32 -> bf16 (returns 16-bit pattern in low bits)
    unsigned int u = __float_as_uint(f);
    unsigned int r = u + 0x7FFFu + ((u >> 16) & 1u);
    return r >> 16;
}

// ---- conversion kernels: 8 elems / thread, 16B stores ----
__global__ __launch_bounds__(256) void cvt_f32_bf16(const float4* __restrict__ in,
                                                    uint4* __restrict__ outp) {
    int i = blockIdx.x * 256 + threadIdx.x;
    float4 a = in[2 * i];
    float4 b = in[2 * i + 1];
    uint4 o;
    o.x = f2bf(a.x) | (f2bf(a.y) << 16);
    o.y = f2bf(a.z) | (f2bf(a.w) << 16);
    o.z = f2bf(b.x) | (f2bf(b.y) << 16);
    o.w = f2bf(b.z) | (f2bf(b.w) << 16);
    outp[i] = o;
}

__global__ __launch_bounds__(256) void cvt_i32_bf16(const int4* __restrict__ in,
                                                    uint4* __restrict__ outp) {
    int i = blockIdx.x * 256 + threadIdx.x;
    int4 a = in[2 * i];
    int4 b = in[2 * i + 1];
    uint4 o;  // |w| <= 127: int -> fp32 -> bf16 is exact
    o.x = f2bf((float)a.x) | (f2bf((float)a.y) << 16);
    o.y = f2bf((float)a.z) | (f2bf((float)a.w) << 16);
    o.z = f2bf((float)b.x) | (f2bf((float)b.y) << 16);
    o.w = f2bf((float)b.z) | (f2bf((float)b.w) << 16);
    outp[i] = o;
}

// ---- GEMM ----
// global_load_lds: per-lane dest = wave-uniform LDS base + lane*16 (m104/m108).
#define GLOAD_LDS16(gsrc, ldst)                                                        \
    __builtin_amdgcn_global_load_lds(                                                  \
        (const __attribute__((address_space(1))) void*)(gsrc),                         \
        (__attribute__((address_space(3))) void*)(ldst), 16, 0, 0)

__global__ __launch_bounds__(256) void gemm_bf16(const ushort_t* __restrict__ xb,
                                                 const ushort_t* __restrict__ wb,
                                                 const float* __restrict__ scale,
                                                 const float* __restrict__ bias,
                                                 float* __restrict__ out) {
    // LDS tiles: 128 rows x 64 cols bf16, stored as 8 granules of 16B per row.
    // XOR swizzle: logical granule g of row r lives at physical granule r*8 + (g ^ (r&7)).
    __shared__ __align__(16) ushort_t As[128 * 64];
    __shared__ __align__(16) ushort_t Bs[128 * 64];

    const int tid  = threadIdx.x;
    const int wave = tid >> 6;
    const int lane = tid & 63;
    const int q    = lane >> 4;    // quad within wave
    const int l16  = lane & 15;
    const int wm   = wave >> 1;    // wave row (0..1)
    const int wn   = wave & 1;     // wave col (0..1)

    const size_t rowBase = (size_t)blockIdx.y * 128;
    const size_t colBase = (size_t)blockIdx.x * 128;

    const ushort_t* Ag = xb + rowBase * GEMM_K;
    const ushort_t* Bg = wb + colBase * GEMM_K;

    // staging: thread covers physical granule P = s*256 + tid; row r = P>>3,
    // phys pos p = tid&7, logical granule g = p ^ (r&7)  (r&7 == (tid>>3)&7)
    const int srow = tid >> 3;                               // 0..31 (+ s*32)
    const int scol = (((tid & 7) ^ (srow & 7)) << 3);        // element col in tile
    const int xr   = l16 & 7;                                // read-side xor key

    floatx4 acc[4][4] = {};

    for (int kt = 0; kt < GEMM_K; kt += 64) {
        __syncthreads();  // previous iteration's frag reads done before overwrite
#pragma unroll
        for (int s = 0; s < 4; ++s) {
            GLOAD_LDS16(Ag + (size_t)(s * 32 + srow) * GEMM_K + kt + scol,
                        &As[(s * 256 + wave * 64) * 8]);
            GLOAD_LDS16(Bg + (size_t)(s * 32 + srow) * GEMM_K + kt + scol,
                        &Bs[(s * 256 + wave * 64) * 8]);
        }
        __syncthreads();  // compiler drains vmcnt before s_barrier

#pragma unroll
        for (int ks = 0; ks < 2; ++ks) {
            bf16x8 af[4], bfr[4];
#pragma unroll
            for (int i = 0; i < 4; ++i) {
                const int m  = wm * 64 + i * 16 + l16;       // A row (M dim)
                const int gA = (ks * 4 + q) ^ xr;            // swizzled granule
                af[i] = *(const bf16x8*)&As[(m * 8 + gA) * 8];
            }
#pragma unroll
            for (int j = 0; j < 4; ++j) {
                const int n  = wn * 64 + j * 16 + l16;       // B row (N dim)
                const int gB = (ks * 4 + q) ^ xr;
                bfr[j] = *(const bf16x8*)&Bs[(n * 8 + gB) * 8];
            }
#pragma unroll
            for (int i = 0; i < 4; ++i)
#pragma unroll
                for (int j = 0; j < 4; ++j)
                    acc[i][j] = __builtin_amdgcn_mfma_f32_16x16x32_bf16(
                        af[i], bfr[j], acc[i][j], 0, 0, 0);
        }
    }

    // epilogue: C/D layout col=lane&15, row=(lane>>4)*4+reg  (m89/m91 verified)
    float scl[4], bs[4];
#pragma unroll
    for (int j = 0; j < 4; ++j) {
        const size_t col = colBase + wn * 64 + j * 16 + l16;
        scl[j] = scale[col];
        bs[j]  = bias[col];
    }
#pragma unroll
    for (int i = 0; i < 4; ++i) {
        const size_t row0 = rowBase + wm * 64 + i * 16 + q * 4;
#pragma unroll
        for (int r = 0; r < 4; ++r) {
            float* orow = out + (row0 + r) * (size_t)GEMM_N;
#pragma unroll
            for (int j = 0; j < 4; ++j) {
                const size_t col = colBase + wn * 64 + j * 16 + l16;
                orow[col] = acc[i][j][r] * scl[j] + bs[j];
            }
        }
    }
}

extern "C" void kernel_launch(void* const* d_in, const int* in_sizes, int n_in,
                              void* d_out, int out_size, void* d_ws, size_t ws_size,
                              hipStream_t stream) {
    const float* x     = (const float*)d_in[0];   // (4,2048,4096) fp32
    const int*   w     = (const int*)d_in[1];     // (16384,4096) int32 in [-127,127]
    const float* scale = (const float*)d_in[2];   // (16384,1) fp32
    const float* bias  = (const float*)d_in[3];   // (16384,) fp32
    float*       out   = (float*)d_out;           // (4,2048,16384) fp32

    ushort_t* xb = (ushort_t*)d_ws;                                   // 64 MB
    ushort_t* wb = (ushort_t*)d_ws + (size_t)GEMM_M * GEMM_K;         // 128 MB

    // x: 33.55M elems / 8 per thread / 256 per block = 16384 blocks
    cvt_f32_bf16<<<(GEMM_M * (size_t)GEMM_K) / 8 / 256, 256, 0, stream>>>(
        (const float4*)x, (uint4*)xb);
    // w: 67.1M elems -> 32768 blocks
    cvt_i32_bf16<<<((size_t)GEMM_N * GEMM_K) / 8 / 256, 256, 0, stream>>>(
        (const int4*)w, (uint4*)wb);

    dim3 grid(GEMM_N / 128, GEMM_M / 128);  // (128, 64) = 8192 blocks
    gemm_bf16<<<grid, dim3(256), 0, stream>>>(xb, wb, scale, bias, out);
}